// Round 1
// baseline (62.052 us; speedup 1.0000x reference)
//
#include <hip/hip_runtime.h>

// 9-qubit quanvolution: one 64-lane wave simulates one (patch, k) circuit.
// State has 2^9 = 512 complex amplitudes; amplitude index a (0..511):
//   bit of qubit q is (a >> (8-q)) & 1   (qubit 0 = MSB, per reshape((2,)*9))
// Mapping: a = lane*8 + r  ->  qubits 0..5 on lane bits (qubit q <-> lane bit 5-q),
//                              qubits 6,7,8 on r bits 2,1,0.
// 8 gate pairs (CRZ then CRX), constants from the reference GATES list.

#define NPATCH_PER_B 484  // 22*22
#define NPATCH 968        // 2*484
#define K 32
#define NWAVES (NPATCH * K)

__global__ __launch_bounds__(256) void quanv_kernel(const float* __restrict__ x,
                                                    const float* __restrict__ qp,
                                                    float* __restrict__ out) {
    const int wid  = blockIdx.x * 4 + (threadIdx.x >> 6);
    const int lane = threadIdx.x & 63;
    if (wid >= NWAVES) return;

    const int k   = wid & 31;
    const int p   = wid >> 5;
    const int b   = p / NPATCH_PER_B;
    const int rem = p - b * NPATCH_PER_B;
    const int pi_ = rem / 22;           // patch row origin
    const int pj  = rem - pi_ * 22;     // patch col origin

    // ---- load 3x3 patch, compute cos/sin(pi*d/2) per qubit ----
    float cq[9], sq[9];
#pragma unroll
    for (int q = 0; q < 9; ++q) {
        const int qi = q / 3, qj = q % 3;
        const float d = x[(b * 24 + (pi_ + qi)) * 24 + (pj + qj)];
        const float h = 1.57079632679489662f * d;   // pi*d/2
        __sincosf(h, &sq[q], &cq[q]);
    }

    // ---- initial product state: amp[a] = m(a) * (-i)^popcount(a) ----
    float ml = 1.f;
#pragma unroll
    for (int q = 0; q < 6; ++q) ml *= ((lane >> (5 - q)) & 1) ? sq[q] : cq[q];
    const int pcl = __popc(lane);

    float ar[8], ai[8];
#pragma unroll
    for (int r = 0; r < 8; ++r) {
        float m = ml;
        m *= (r & 4) ? sq[6] : cq[6];
        m *= (r & 2) ? sq[7] : cq[7];
        m *= (r & 1) ? sq[8] : cq[8];
        const int pc = (pcl + __popc(r)) & 3;   // (-i)^pc
        ar[r] = (pc == 0) ? m : ((pc == 2) ? -m : 0.f);
        ai[r] = (pc == 1) ? -m : ((pc == 3) ? m : 0.f);
    }

    // ---- 8 gate pairs ----
    const float* th = qp + k * 16;
    constexpr int GC[8] = {1, 3, 2, 8, 5, 7, 6, 4};   // control qubit
    constexpr int GT[8] = {0, 2, 0, 7, 4, 6, 4, 0};   // target qubit
#pragma unroll
    for (int g = 0; g < 8; ++g) {
        const int c = GC[g], t = GT[g];

        // CRZ(theta): amp *= exp(+/- i*theta/2) where control bit == 1
        float cz, sz;
        __sincosf(th[2 * g] * 0.5f, &sz, &cz);
#pragma unroll
        for (int r = 0; r < 8; ++r) {
            const int a = (lane << 3) | r;
            if ((a >> (8 - c)) & 1) {
                const float sgn = ((a >> (8 - t)) & 1) ? 1.f : -1.f;
                const float nr = ar[r] * cz - sgn * ai[r] * sz;
                const float ni = ai[r] * cz + sgn * ar[r] * sz;
                ar[r] = nr; ai[r] = ni;
            }
        }

        // CRX(theta): new = cos*amp - i*sin*partner, on control==1 subspace
        float cx, sx;
        __sincosf(th[2 * g + 1] * 0.5f, &sx, &cx);
        if (t >= 6) {
            // in-lane pair: partner register r ^ rm
            const int rm = 1 << (8 - t);
#pragma unroll
            for (int r = 0; r < 8; ++r) {
                if (r & rm) continue;
                const int r1 = r | rm;
                const int a0 = (lane << 3) | r;
                if ((a0 >> (8 - c)) & 1) {
                    const float n0r = cx * ar[r]  + sx * ai[r1];
                    const float n0i = cx * ai[r]  - sx * ar[r1];
                    const float n1r = cx * ar[r1] + sx * ai[r];
                    const float n1i = cx * ai[r1] - sx * ar[r];
                    ar[r] = n0r; ai[r] = n0i;
                    ar[r1] = n1r; ai[r1] = n1i;
                }
            }
        } else {
            // cross-lane pair: partner lane = lane ^ (1 << (5-t))
            const int lm = 1 << (5 - t);
#pragma unroll
            for (int r = 0; r < 8; ++r) {
                const float pr = __shfl_xor(ar[r], lm, 64);
                const float pim = __shfl_xor(ai[r], lm, 64);
                const int a = (lane << 3) | r;
                if ((a >> (8 - c)) & 1) {
                    const float nr = cx * ar[r] + sx * pim;
                    const float ni = cx * ai[r] - sx * pr;
                    ar[r] = nr; ai[r] = ni;
                }
            }
        }
    }

    // ---- measurement of qubit 0 (a bit 8 = lane bit 5) ----
    float s = 0.f;
#pragma unroll
    for (int r = 0; r < 8; ++r) s += ar[r] * ar[r] + ai[r] * ai[r];
    if ((lane >> 5) & 1) s = -s;       // p0 - p1
#pragma unroll
    for (int m = 32; m >= 1; m >>= 1) s += __shfl_xor(s, m, 64);

    if (lane == 0) {
        // out[b, pi_+1, pj+1, k]
        out[((b * 24 + (pi_ + 1)) * 24 + (pj + 1)) * K + k] = (s + 1.f) * 0.5f;
    }
}

extern "C" void kernel_launch(void* const* d_in, const int* in_sizes, int n_in,
                              void* d_out, int out_size, void* d_ws, size_t ws_size,
                              hipStream_t stream) {
    const float* x  = (const float*)d_in[0];   // (2,24,24,1) f32
    const float* qp = (const float*)d_in[1];   // (32,16) f32
    float* out = (float*)d_out;                // (2,24,24,32) f32

    // Border must be zero (reference scatters interior into zeros); harness
    // poisons d_out with 0xAA, so clear every call.
    hipMemsetAsync(out, 0, (size_t)out_size * sizeof(float), stream);

    const int nblocks = (NWAVES + 3) / 4;      // 4 waves (256 threads) per block
    quanv_kernel<<<nblocks, 256, 0, stream>>>(x, qp, out);
}

// Round 2
// 9.345 us; speedup vs baseline: 6.6401x; 6.6401x over previous
//
#include <hip/hip_runtime.h>

// Quanvolution 3x3, 9 qubits, 8 CRZ+CRX pairs — exact Bloch-vector collapse.
//
// Gate list (control c, target t, thetas th[2g], th[2g+1]):
//   (1,0) (3,2) (2,0) (8,7) (5,4) (7,6) (6,4) (4,0)
// Every gate's control and target are in a product state at gate time
// (cluster structure {0,1}x{2,3} -> {0..3}, {4,5}x{6,7,8} -> {4..8}, then A x B),
// and controls are only ever read via their Z populations, which all these
// (control-diagonal) gates preserve. Hence, exactly:
//   target Bloch r' = (1-p) * r + p * RX(th_b) RZ(th_a) r,  p = P(control=1)
// with SO(3) maps (Schrodinger convention, verified vs statevector):
//   RZ(f): x' = x cf - y sf ; y' = y cf + x sf ; z' = z
//   RX(t): x' = x ; y' = y ct - z st ; z' = z ct + y st
// Initial qubit q: RX(pi*d_q)|0> -> Bloch (0, -sin(pi d), cos(pi d)),
// P(q=1) = (1 - cos(pi d))/2. Output = (z_0_final + 1)/2.

#define K 32
#define TOT (2 * 24 * 24 * K)  // 36864

struct B3 { float x, y, z; };

__device__ __forceinline__ void cpair(B3& r, float p, float tha, float thb) {
    float ca, sa, cb, sb;
    __sincosf(tha, &sa, &ca);
    __sincosf(thb, &sb, &cb);
    const float rx = r.x * ca - r.y * sa;          // RZ
    const float ry = r.y * ca + r.x * sa;
    const float ny = ry * cb - r.z * sb;           // RX
    const float nz = r.z * cb + ry * sb;
    r.x += p * (rx - r.x);                          // blend with control prob
    r.y += p * (ny - r.y);
    r.z += p * (nz - r.z);
}

__global__ __launch_bounds__(256) void quanv_kernel(const float* __restrict__ x,
                                                    const float* __restrict__ qp,
                                                    float* __restrict__ out) {
    const int t = blockIdx.x * 256 + threadIdx.x;   // grid exactly covers TOT
    const int k = t & 31;
    const int rest = t >> 5;                        // b*576 + i*24 + j
    const int j = rest % 24;
    const int bi = rest / 24;
    const int i = bi % 24;
    const int b = bi / 24;

    if (i == 0 || i == 23 || j == 0 || j == 23) { out[t] = 0.f; return; }

    // 3x3 patch at origin (i-1, j-1): per-pixel sin/cos of pi*d
    const float* xb = x + (b * 24 + (i - 1)) * 24 + (j - 1);
    float cz[9], sz[9];
#pragma unroll
    for (int q = 0; q < 9; ++q) {
        const float d = xb[(q / 3) * 24 + (q % 3)];
        __sincosf(3.14159265358979323846f * d, &sz[q], &cz[q]);
    }
    // initial Bloch (0, -sin, cos); initial P(1) = (1-cos)/2
    const float* th = qp + k * 16;

    B3 r0 = {0.f, -sz[0], cz[0]};
    B3 r2 = {0.f, -sz[2], cz[2]};
    B3 r4 = {0.f, -sz[4], cz[4]};
    B3 r6 = {0.f, -sz[6], cz[6]};
    B3 r7 = {0.f, -sz[7], cz[7]};

    const float p1 = 0.5f * (1.f - cz[1]);
    const float p3 = 0.5f * (1.f - cz[3]);
    const float p5 = 0.5f * (1.f - cz[5]);
    const float p8 = 0.5f * (1.f - cz[8]);

    cpair(r0, p1, th[0], th[1]);                 // gate (1,0)
    cpair(r2, p3, th[2], th[3]);                 // gate (3,2)
    const float p2 = 0.5f * (1.f - r2.z);
    cpair(r0, p2, th[4], th[5]);                 // gate (2,0)
    cpair(r7, p8, th[6], th[7]);                 // gate (8,7)
    const float p7 = 0.5f * (1.f - r7.z);
    cpair(r4, p5, th[8], th[9]);                 // gate (5,4)
    cpair(r6, p7, th[10], th[11]);               // gate (7,6)
    const float p6 = 0.5f * (1.f - r6.z);
    cpair(r4, p6, th[12], th[13]);               // gate (6,4)
    const float p4 = 0.5f * (1.f - r4.z);
    cpair(r0, p4, th[14], th[15]);               // gate (4,0)

    out[t] = (r0.z + 1.f) * 0.5f;
}

extern "C" void kernel_launch(void* const* d_in, const int* in_sizes, int n_in,
                              void* d_out, int out_size, void* d_ws, size_t ws_size,
                              hipStream_t stream) {
    const float* x  = (const float*)d_in[0];   // (2,24,24,1) f32
    const float* qp = (const float*)d_in[1];   // (32,16) f32
    float* out = (float*)d_out;                // (2,24,24,32) f32
    quanv_kernel<<<TOT / 256, 256, 0, stream>>>(x, qp, out);  // border zeros included
}